// Round 4
// baseline (505.251 us; speedup 1.0000x reference)
//
#include <hip/hip_runtime.h>
#include <hip/hip_bf16.h>
#include <math.h>

#define WINDOW 4
#define NNODES 50000
#define NEDGES 400000
#define DIM 128
#define BM 64

// multi-split geometry: coarse bucket = dst >> 9 (512 dsts per bucket)
#define BSH 9
#define BSZ 512
#define NB2 ((NNODES + BSZ - 1) / BSZ)         // 98 buckets
#define EPB 4096                               // edges per p1/bhist block
#define P1B ((NEDGES + EPB - 1) / EPB)         // 98 blocks per window

typedef short bf16x8 __attribute__((ext_vector_type(8)));
typedef float f32x4  __attribute__((ext_vector_type(4)));

__device__ __forceinline__ float eluf(float x) {
    return x > 0.0f ? x : expm1f(x);
}
__device__ __forceinline__ float bf16_lo(unsigned int v) {
    return __uint_as_float(v << 16);
}
__device__ __forceinline__ float bf16_hi(unsigned int v) {
    return __uint_as_float(v & 0xffff0000u);
}
__device__ __forceinline__ unsigned short f2bf(float f) {
    __hip_bfloat16 h = __float2bfloat16(f);   // RNE
    return *(unsigned short*)&h;
}

// ---- prep: zero bcnt/bcur + cast/transpose W0,W1 -> wt[nb][2][128][128] ----
__global__ __launch_bounds__(256) void prep_kernel(
    const float* __restrict__ W0, const float* __restrict__ W1,
    unsigned short* __restrict__ wt, int* __restrict__ bcnt,
    int* __restrict__ bcur, int nb)
{
    int i = blockIdx.x * 256 + threadIdx.x;
    int ncast = nb * 2 * DIM * DIM;            // nb*32768
    if (i < ncast) {
        int w   = i >> 15;
        int rem = i & 32767;
        int m   = rem >> 14;                   // 0:W0 1:W1
        int j   = rem & 16383;
        int n   = j >> 7, k = j & 127;
        const float* Ws = (m ? W1 : W0) + (size_t)w * DIM * DIM;
        wt[i] = f2bf(Ws[k * DIM + n]);         // wt[(w*2+m)*16384 + n*128 + k]
    }
    if (i < nb * NB2) { bcnt[i] = 0; bcur[i] = 0; }
}

// ---- bhist: block-aggregated coarse histogram (<=98 global atomics/block) ----
__global__ __launch_bounds__(256) void bhist_kernel(
    const int* __restrict__ ei, int* __restrict__ bcnt)
{
    const int w = blockIdx.y, b0 = blockIdx.x * EPB;
    const int t = threadIdx.x;
    __shared__ int lh[NB2];
    for (int i = t; i < NB2; i += 256) lh[i] = 0;
    __syncthreads();
    const int* dst = ei + (size_t)w * 2 * NEDGES + NEDGES;
    #pragma unroll
    for (int j = 0; j < EPB / 256; ++j) {
        int e = b0 + j * 256 + t;
        if (e < NEDGES) atomicAdd(&lh[dst[e] >> BSH], 1);
    }
    __syncthreads();
    for (int i = t; i < NB2; i += 256)
        if (lh[i]) atomicAdd(&bcnt[w * NB2 + i], lh[i]);
}

// ---- bscan: exclusive scan of 98 bucket counts (one 128-thr block/window) ----
__global__ __launch_bounds__(128) void bscan_kernel(
    const int* __restrict__ bcnt, int* __restrict__ bbase, int* __restrict__ offs)
{
    const int w = blockIdx.x;
    const int t = threadIdx.x;
    __shared__ int s[128];
    int orig = (t < NB2) ? bcnt[w * NB2 + t] : 0;
    s[t] = orig;
    __syncthreads();
    for (int off = 1; off < 128; off <<= 1) {
        int v = (t >= off) ? s[t - off] : 0;
        __syncthreads();
        s[t] += v;
        __syncthreads();
    }
    if (t < NB2) bbase[w * (NB2 + 1) + t] = s[t] - orig;       // exclusive
    if (t == NB2 - 1) {
        bbase[w * (NB2 + 1) + NB2] = s[t];                     // total == NEDGES
        offs[(size_t)w * (NNODES + 1) + NNODES] = s[t];
    }
}

// ---- bucket_p1: block multi-split. One global atomic per (block,bucket); ----
// ---- each bucket's run written as a contiguous burst by a single block. ----
__global__ __launch_bounds__(256) void bucket_p1(
    const int* __restrict__ ei, const float* __restrict__ ew,
    const int* __restrict__ bbase, int* __restrict__ bcur,
    int2* __restrict__ stage)
{
    const int w = blockIdx.y, b0 = blockIdx.x * EPB;
    const int t = threadIdx.x;
    __shared__ int lh[NB2];
    __shared__ int gb[NB2];
    for (int i = t; i < NB2; i += 256) lh[i] = 0;
    __syncthreads();
    const int*   eiw = ei + (size_t)w * 2 * NEDGES;
    const float* eww = ew + (size_t)w * NEDGES;
    int  tag[EPB / 256];           // (bucket<<12) | local_rank, -1 = invalid
    int2 pk[EPB / 256];
    #pragma unroll
    for (int j = 0; j < EPB / 256; ++j) {
        int e = b0 + j * 256 + t;
        if (e < NEDGES) {
            int d = eiw[NEDGES + e], s = eiw[e];
            int b = d >> BSH;
            int r = atomicAdd(&lh[b], 1);      // local rank within (block,bucket)
            tag[j] = (b << 12) | r;            // r < 4096
            pk[j]  = make_int2(s | ((d & (BSZ - 1)) << 16),
                               __float_as_int(eww[e]));
        } else tag[j] = -1;
    }
    __syncthreads();
    for (int i = t; i < NB2; i += 256)
        gb[i] = bbase[w * (NB2 + 1) + i]
              + (lh[i] ? atomicAdd(&bcur[w * NB2 + i], lh[i]) : 0);
    __syncthreads();
    int2* st = stage + (size_t)w * NEDGES;
    #pragma unroll
    for (int j = 0; j < EPB / 256; ++j) {
        if (tag[j] >= 0)
            st[gb[tag[j] >> 12] + (tag[j] & 4095)] = pk[j];
    }
}

// ---- bucket_p2: per-bucket per-dst sort -> offs[dst] + dst-sorted srcw ----
// One block per (bucket, window): ~4K edges, dense 32KB output (full lines).
// Also produces the per-dst CSR offsets (replaces hist + 3-phase scan).
__global__ __launch_bounds__(256) void bucket_p2(
    const int2* __restrict__ stage, const int* __restrict__ bbase,
    int* __restrict__ offs, int2* __restrict__ srcw)
{
    const int b = blockIdx.x, w = blockIdx.y;
    const int t = threadIdx.x;
    __shared__ int s[BSZ];
    const int base = bbase[w * (NB2 + 1) + b];
    const int n    = bbase[w * (NB2 + 1) + b + 1] - base;
    s[t] = 0; s[t + 256] = 0;
    __syncthreads();
    const int2* st = stage + (size_t)w * NEDGES + base;
    for (int i = t; i < n; i += 256)
        atomicAdd(&s[(st[i].x >> 16) & (BSZ - 1)], 1);
    __syncthreads();
    int o0 = s[t], o1 = s[t + 256];
    // inclusive Hillis-Steele over 512 counters, 2 elems/thread
    for (int off = 1; off < BSZ; off <<= 1) {
        int a0 = (t >= off) ? s[t - off] : 0;
        int a1 = (t + 256 >= off) ? s[t + 256 - off] : 0;
        __syncthreads();
        s[t] += a0; s[t + 256] += a1;
        __syncthreads();
    }
    int c0 = base + s[t] - o0;                 // absolute exclusive prefix
    int c1 = base + s[t + 256] - o1;
    __syncthreads();
    s[t] = c0; s[t + 256] = c1;                // become scatter cursors
    int* ofw = offs + (size_t)w * (NNODES + 1);
    int n0 = b * BSZ + t, n1 = b * BSZ + t + 256;
    if (n0 < NNODES) ofw[n0] = c0;
    if (n1 < NNODES) ofw[n1] = c1;
    __syncthreads();
    int2* sw = srcw + (size_t)w * NEDGES;
    for (int i = t; i < n; i += 256) {
        int2 e = st[i];
        int pos = atomicAdd(&s[(e.x >> 16) & (BSZ - 1)], 1);
        sw[pos] = make_int2(e.x & 0xffff, e.y);
    }
}

// ---- MFMA GEMM (batched): C_bf16[w] = A'[w] @ W[w], A' = elu(A+bias) if bias ----
__global__ __launch_bounds__(256) void gemm_mfma(
    const void* __restrict__ Avoid, size_t a_stride,        // elements per window
    const unsigned short* __restrict__ WtG, size_t wt_stride,
    const float* __restrict__ bias,                          // null or stride DIM
    unsigned short* __restrict__ C,                          // stride N*DIM
    int a_bf16)
{
    __shared__ unsigned short As[BM][136];
    __shared__ unsigned short Bs[DIM][136];
    const int t  = threadIdx.x;
    const int r0 = blockIdx.x * BM;
    const int w  = blockIdx.y;
    const unsigned short* Wt = WtG + (size_t)w * wt_stride;
    unsigned short* Cw = C + (size_t)w * NNODES * DIM;

    if (a_bf16) {
        const unsigned short* A = (const unsigned short*)Avoid + (size_t)w * a_stride;
        const float* bs = bias + (size_t)w * DIM;
        #pragma unroll
        for (int l = 0; l < 4; ++l) {
            int idx = t + l * 256;             // 1024 uint4 = 64x128 bf16
            int row = idx >> 4, c8 = (idx & 15) << 3;
            int gr  = r0 + row;
            uint4 v = make_uint4(0, 0, 0, 0);
            if (gr < NNODES) v = *(const uint4*)(A + (size_t)gr * DIM + c8);
            union { uint4 u; unsigned short s[8]; } in, ot;
            in.u = v;
            #pragma unroll
            for (int j = 0; j < 8; ++j) {
                float f = __uint_as_float((unsigned int)in.s[j] << 16);
                ot.s[j] = f2bf(eluf(f + bs[c8 + j]));
            }
            *(uint4*)&As[row][c8] = ot.u;
        }
    } else {
        const float* A = (const float*)Avoid + (size_t)w * a_stride;
        #pragma unroll
        for (int l = 0; l < 8; ++l) {
            int idx = t + l * 256;             // 2048 float4 = 64x128 fp32
            int row = idx >> 5, c4 = (idx & 31) << 2;
            int gr  = r0 + row;
            float4 v = make_float4(0.f, 0.f, 0.f, 0.f);
            if (gr < NNODES) v = *(const float4*)(A + (size_t)gr * DIM + c4);
            union { uint2 u; unsigned short s[4]; } ot;
            ot.s[0] = f2bf(v.x); ot.s[1] = f2bf(v.y);
            ot.s[2] = f2bf(v.z); ot.s[3] = f2bf(v.w);
            *(uint2*)&As[row][c4] = ot.u;
        }
    }
    // full W^T: 128x128 bf16 = 2048 uint4 chunks
    #pragma unroll
    for (int l = 0; l < 8; ++l) {
        int idx = t + l * 256;
        int n = idx >> 4, k8 = (idx & 15) << 3;
        *(uint4*)&Bs[n][k8] = *(const uint4*)(Wt + (size_t)n * DIM + k8);
    }
    __syncthreads();

    const int lane = t & 63, wv = t >> 6;
    const int mr = lane & 15, quad = lane >> 4;

    f32x4 acc[8];
    #pragma unroll
    for (int c = 0; c < 8; ++c) acc[c] = (f32x4){0.f, 0.f, 0.f, 0.f};

    const unsigned short* aptr = &As[wv * 16 + mr][quad * 8];
    #pragma unroll
    for (int kc = 0; kc < DIM; kc += 32) {
        bf16x8 a = *(const bf16x8*)(aptr + kc);
        #pragma unroll
        for (int c = 0; c < 8; ++c) {
            bf16x8 b = *(const bf16x8*)(&Bs[c * 16 + mr][quad * 8 + kc]);
            acc[c] = __builtin_amdgcn_mfma_f32_16x16x32_bf16(a, b, acc[c], 0, 0, 0);
        }
    }
    // Epilogue: bounce C tile through LDS (reuse As) -> coalesced uint4 stores
    __syncthreads();
    const int lr0 = wv * 16 + quad * 4;
    #pragma unroll
    for (int c = 0; c < 8; ++c) {
        int col = c * 16 + mr;
        #pragma unroll
        for (int r = 0; r < 4; ++r)
            As[lr0 + r][col] = f2bf(acc[c][r]);   // C/D: col=lane&15, row=quad*4+r
    }
    __syncthreads();
    #pragma unroll
    for (int l = 0; l < 4; ++l) {
        int idx = t + l * 256;                 // 1024 = 64 rows x 16 chunks
        int row = idx >> 4, c8 = (idx & 15) << 3;
        int gr = r0 + row;
        if (gr < NNODES)
            *(uint4*)(Cw + (size_t)gr * DIM + c8) = *(const uint4*)&As[row][c8];
    }
}

// ---- gather_agg (batched): one wave per dst, 4x16 edge-slot layout ----
// Four 16-lane slots each load one edge's full 256B row as dwordx4 (8 dims/lane).
// ceil(deg/4) trips, weight-masked remainder, 2 shfl_xor to combine slots.
// mode 0: agg_bf16[w][dst] = sum.  mode 1: out_f32[w][dst] = elu(sum + bias).
__global__ __launch_bounds__(256) void gather_agg(
    const unsigned short* __restrict__ h,
    const int*  __restrict__ offs,
    const int2* __restrict__ srcw,
    const float* __restrict__ bias,
    void* __restrict__ outp,
    int mode)
{
    const int w = blockIdx.y;
    const unsigned short* hw = h + (size_t)w * NNODES * DIM;
    const int*  ow = offs + (size_t)w * (NNODES + 1);
    const int2* sw = srcw + (size_t)w * NEDGES;
    int wid  = (blockIdx.x * 256 + threadIdx.x) >> 6;
    int lane = threadIdx.x & 63;
    if (wid >= NNODES) return;
    const int beg = ow[wid], end = ow[wid + 1];
    const int g  = lane >> 4;                  // edge slot 0..3
    const int d0 = (lane & 15) << 3;           // 8 dims per lane

    float acc[8];
    #pragma unroll
    for (int j = 0; j < 8; ++j) acc[j] = 0.f;

    #pragma unroll 2
    for (int e0 = beg; e0 < end; e0 += 4) {
        int e  = e0 + g;
        int ee = min(e, end - 1);              // safe: e0 < end => end-1 >= beg
        int2 p = sw[ee];
        float wf = (e < end) ? __int_as_float(p.y) : 0.f;
        uint4 v = *(const uint4*)(hw + (size_t)p.x * DIM + d0);
        acc[0] += wf * bf16_lo(v.x); acc[1] += wf * bf16_hi(v.x);
        acc[2] += wf * bf16_lo(v.y); acc[3] += wf * bf16_hi(v.y);
        acc[4] += wf * bf16_lo(v.z); acc[5] += wf * bf16_hi(v.z);
        acc[6] += wf * bf16_lo(v.w); acc[7] += wf * bf16_hi(v.w);
    }
    #pragma unroll
    for (int j = 0; j < 8; ++j) {
        acc[j] += __shfl_xor(acc[j], 16, 64);
        acc[j] += __shfl_xor(acc[j], 32, 64);
    }

    if (mode == 0) {
        if (g == 0) {
            union { uint4 u; unsigned short s[8]; } o;
            #pragma unroll
            for (int j = 0; j < 8; ++j) o.s[j] = f2bf(acc[j]);
            *(uint4*)((unsigned short*)outp + (size_t)w * NNODES * DIM
                      + (size_t)wid * DIM + d0) = o.u;
        }
    } else {
        const float* bs = bias + (size_t)w * DIM;
        float* op = (float*)outp + (size_t)w * NNODES * DIM + (size_t)wid * DIM;
        if (g == 0) {
            float4 r;
            r.x = eluf(acc[0] + bs[d0 + 0]);
            r.y = eluf(acc[1] + bs[d0 + 1]);
            r.z = eluf(acc[2] + bs[d0 + 2]);
            r.w = eluf(acc[3] + bs[d0 + 3]);
            *(float4*)(op + d0) = r;
        } else if (g == 1) {
            float4 r;
            r.x = eluf(acc[4] + bs[d0 + 4]);
            r.y = eluf(acc[5] + bs[d0 + 5]);
            r.z = eluf(acc[6] + bs[d0 + 6]);
            r.w = eluf(acc[7] + bs[d0 + 7]);
            *(float4*)(op + d0 + 4) = r;
        }
    }
}

extern "C" void kernel_launch(void* const* d_in, const int* in_sizes, int n_in,
                              void* d_out, int out_size, void* d_ws, size_t ws_size,
                              hipStream_t stream) {
    const float* x           = (const float*)d_in[0];
    const int*   edge_index  = (const int*)  d_in[1];
    const float* edge_weight = (const float*)d_in[2];
    const float* W0          = (const float*)d_in[3];
    const float* b0          = (const float*)d_in[4];
    const float* W1          = (const float*)d_in[5];
    const float* b1          = (const float*)d_in[6];
    float*       out         = (float*)d_out;

    const size_t ND = (size_t)NNODES * DIM;

    // Workspace per batched-window: h + agg (bf16) + wt + srcw + offs + bucket meta
    auto need = [&](int nb) -> size_t {
        return (size_t)nb * (ND * 2 + ND * 2 + 2 * DIM * DIM * 2
                             + (size_t)NEDGES * 8
                             + (size_t)(NNODES + 1) * 4
                             + (size_t)NB2 * 4 * 2 + (size_t)(NB2 + 1) * 4);
    };
    int nb = WINDOW;
    while (nb > 1 && need(nb) > ws_size) nb >>= 1;

    char* p = (char*)d_ws;
    unsigned short* h_buf   = (unsigned short*)p;  p += (size_t)nb * ND * 2;
    unsigned short* agg_buf = (unsigned short*)p;  p += (size_t)nb * ND * 2;
    unsigned short* wt      = (unsigned short*)p;  p += (size_t)nb * 2 * DIM * DIM * 2;
    int2*           srcw    = (int2*)p;            p += (size_t)nb * NEDGES * 8;
    int*            offs    = (int*)p;             p += (size_t)nb * (NNODES + 1) * 4;
    int*            bcnt    = (int*)p;             p += (size_t)nb * NB2 * 4;
    int*            bcur    = (int*)p;             p += (size_t)nb * NB2 * 4;
    int*            bbase   = (int*)p;             p += (size_t)nb * (NB2 + 1) * 4;
    int2*           stage   = (int2*)h_buf;        // reuse h_buf before gemm hop 1

    const dim3 hg(P1B, nb);                           // multi-split blocks
    const dim3 gg((NNODES + BM - 1) / BM, nb);        // gemm tiles
    const dim3 ag((NNODES * 64 + 255) / 256, nb);     // one wave per dst
    const dim3 bg(NB2, nb);                           // per-bucket pass
    const int  prep_grid = (nb * 2 * DIM * DIM + 255) / 256;

    for (int w0 = 0; w0 < WINDOW; w0 += nb) {
        const float* W0g = W0 + (size_t)w0 * DIM * DIM;
        const float* W1g = W1 + (size_t)w0 * DIM * DIM;
        const int*   eig = edge_index  + (size_t)w0 * 2 * NEDGES;
        const float* ewg = edge_weight + (size_t)w0 * NEDGES;

        prep_kernel <<<prep_grid, 256, 0, stream>>>(W0g, W1g, wt, bcnt, bcur, nb);
        bhist_kernel<<<hg, 256, 0, stream>>>(eig, bcnt);
        bscan_kernel<<<nb, 128, 0, stream>>>(bcnt, bbase, offs);
        bucket_p1   <<<hg, 256, 0, stream>>>(eig, ewg, bbase, bcur, stage);
        bucket_p2   <<<bg, 256, 0, stream>>>(stage, bbase, offs, srcw);

        // hop 1: h = x @ W0 ; agg = gather(h)   (gemm overwrites stage == h_buf)
        gemm_mfma <<<gg, 256, 0, stream>>>(x + (size_t)w0 * ND, ND,
                                           wt, 2 * DIM * DIM, nullptr, h_buf, 0);
        gather_agg<<<ag, 256, 0, stream>>>(h_buf, offs, srcw, nullptr, agg_buf, 0);
        // hop 2: h = elu(agg+b0) @ W1 ; out = elu(gather(h) + b1)
        gemm_mfma <<<gg, 256, 0, stream>>>(agg_buf, ND,
                                           wt + DIM * DIM, 2 * DIM * DIM,
                                           b0 + (size_t)w0 * DIM, h_buf, 1);
        gather_agg<<<ag, 256, 0, stream>>>(h_buf, offs, srcw,
                                           b1 + (size_t)w0 * DIM,
                                           out + (size_t)w0 * ND, 1);
    }
}

// Round 5
// 459.097 us; speedup vs baseline: 1.1005x; 1.1005x over previous
//
#include <hip/hip_runtime.h>
#include <hip/hip_bf16.h>
#include <math.h>

#define WINDOW 4
#define NNODES 50000
#define NEDGES 400000
#define DIM 128
#define BM 64

// multi-split geometry: coarse bucket = dst >> 9 (512 dsts per bucket)
#define BSH 9
#define BSZ 512
#define NB2 ((NNODES + BSZ - 1) / BSZ)         // 98 buckets
#define EPB 4096                               // edges per p1/bhist block
#define P1B ((NEDGES + EPB - 1) / EPB)         // 98 blocks per window

typedef short bf16x8 __attribute__((ext_vector_type(8)));
typedef float f32x4  __attribute__((ext_vector_type(4)));

__device__ __forceinline__ float eluf(float x) {
    return x > 0.0f ? x : expm1f(x);
}
__device__ __forceinline__ float bf16_lo(unsigned int v) {
    return __uint_as_float(v << 16);
}
__device__ __forceinline__ float bf16_hi(unsigned int v) {
    return __uint_as_float(v & 0xffff0000u);
}
__device__ __forceinline__ unsigned short f2bf(float f) {
    __hip_bfloat16 h = __float2bfloat16(f);   // RNE
    return *(unsigned short*)&h;
}

// ---- prep: zero bcnt/bcur + cast/transpose W0,W1 -> wt[nb][2][128][128] ----
__global__ __launch_bounds__(256) void prep_kernel(
    const float* __restrict__ W0, const float* __restrict__ W1,
    unsigned short* __restrict__ wt, int* __restrict__ bcnt,
    int* __restrict__ bcur, int nb)
{
    int i = blockIdx.x * 256 + threadIdx.x;
    int ncast = nb * 2 * DIM * DIM;            // nb*32768
    if (i < ncast) {
        int w   = i >> 15;
        int rem = i & 32767;
        int m   = rem >> 14;                   // 0:W0 1:W1
        int j   = rem & 16383;
        int n   = j >> 7, k = j & 127;
        const float* Ws = (m ? W1 : W0) + (size_t)w * DIM * DIM;
        wt[i] = f2bf(Ws[k * DIM + n]);         // wt[(w*2+m)*16384 + n*128 + k]
    }
    if (i < nb * NB2) { bcnt[i] = 0; bcur[i] = 0; }
}

// ---- bhist: block-aggregated coarse histogram (<=98 global atomics/block) ----
__global__ __launch_bounds__(256) void bhist_kernel(
    const int* __restrict__ ei, int* __restrict__ bcnt)
{
    const int w = blockIdx.y, b0 = blockIdx.x * EPB;
    const int t = threadIdx.x;
    __shared__ int lh[NB2];
    for (int i = t; i < NB2; i += 256) lh[i] = 0;
    __syncthreads();
    const int* dst = ei + (size_t)w * 2 * NEDGES + NEDGES;
    #pragma unroll
    for (int j = 0; j < EPB / 256; ++j) {
        int e = b0 + j * 256 + t;
        if (e < NEDGES) atomicAdd(&lh[dst[e] >> BSH], 1);
    }
    __syncthreads();
    for (int i = t; i < NB2; i += 256)
        if (lh[i]) atomicAdd(&bcnt[w * NB2 + i], lh[i]);
}

// ---- bscan: exclusive scan of 98 bucket counts (one 128-thr block/window) ----
__global__ __launch_bounds__(128) void bscan_kernel(
    const int* __restrict__ bcnt, int* __restrict__ bbase, int* __restrict__ offs)
{
    const int w = blockIdx.x;
    const int t = threadIdx.x;
    __shared__ int s[128];
    int orig = (t < NB2) ? bcnt[w * NB2 + t] : 0;
    s[t] = orig;
    __syncthreads();
    for (int off = 1; off < 128; off <<= 1) {
        int v = (t >= off) ? s[t - off] : 0;
        __syncthreads();
        s[t] += v;
        __syncthreads();
    }
    if (t < NB2) bbase[w * (NB2 + 1) + t] = s[t] - orig;       // exclusive
    if (t == NB2 - 1) {
        bbase[w * (NB2 + 1) + NB2] = s[t];                     // total == NEDGES
        offs[(size_t)w * (NNODES + 1) + NNODES] = s[t];
    }
}

// ---- bucket_p1: block multi-split. One global atomic per (block,bucket); ----
// ---- each bucket's run written as a contiguous burst by a single block. ----
__global__ __launch_bounds__(256) void bucket_p1(
    const int* __restrict__ ei, const float* __restrict__ ew,
    const int* __restrict__ bbase, int* __restrict__ bcur,
    int2* __restrict__ stage)
{
    const int w = blockIdx.y, b0 = blockIdx.x * EPB;
    const int t = threadIdx.x;
    __shared__ int lh[NB2];
    __shared__ int gb[NB2];
    for (int i = t; i < NB2; i += 256) lh[i] = 0;
    __syncthreads();
    const int*   eiw = ei + (size_t)w * 2 * NEDGES;
    const float* eww = ew + (size_t)w * NEDGES;
    int  tag[EPB / 256];           // (bucket<<12) | local_rank, -1 = invalid
    int2 pk[EPB / 256];
    #pragma unroll
    for (int j = 0; j < EPB / 256; ++j) {
        int e = b0 + j * 256 + t;
        if (e < NEDGES) {
            int d = eiw[NEDGES + e], s = eiw[e];
            int b = d >> BSH;
            int r = atomicAdd(&lh[b], 1);      // local rank within (block,bucket)
            tag[j] = (b << 12) | r;            // r < 4096
            pk[j]  = make_int2(s | ((d & (BSZ - 1)) << 16),
                               __float_as_int(eww[e]));
        } else tag[j] = -1;
    }
    __syncthreads();
    for (int i = t; i < NB2; i += 256)
        gb[i] = bbase[w * (NB2 + 1) + i]
              + (lh[i] ? atomicAdd(&bcur[w * NB2 + i], lh[i]) : 0);
    __syncthreads();
    int2* st = stage + (size_t)w * NEDGES;
    #pragma unroll
    for (int j = 0; j < EPB / 256; ++j) {
        if (tag[j] >= 0)
            st[gb[tag[j] >> 12] + (tag[j] & 4095)] = pk[j];
    }
}

// ---- bucket_p2: per-bucket per-dst sort -> offs[dst] + dst-sorted srcw ----
// One block per (bucket, window): ~4K edges, dense 32KB output (full lines).
// Also produces the per-dst CSR offsets (replaces hist + 3-phase scan).
__global__ __launch_bounds__(256) void bucket_p2(
    const int2* __restrict__ stage, const int* __restrict__ bbase,
    int* __restrict__ offs, int2* __restrict__ srcw)
{
    const int b = blockIdx.x, w = blockIdx.y;
    const int t = threadIdx.x;
    __shared__ int s[BSZ];
    const int base = bbase[w * (NB2 + 1) + b];
    const int n    = bbase[w * (NB2 + 1) + b + 1] - base;
    s[t] = 0; s[t + 256] = 0;
    __syncthreads();
    const int2* st = stage + (size_t)w * NEDGES + base;
    for (int i = t; i < n; i += 256)
        atomicAdd(&s[(st[i].x >> 16) & (BSZ - 1)], 1);
    __syncthreads();
    int o0 = s[t], o1 = s[t + 256];
    // inclusive Hillis-Steele over 512 counters, 2 elems/thread
    for (int off = 1; off < BSZ; off <<= 1) {
        int a0 = (t >= off) ? s[t - off] : 0;
        int a1 = (t + 256 >= off) ? s[t + 256 - off] : 0;
        __syncthreads();
        s[t] += a0; s[t + 256] += a1;
        __syncthreads();
    }
    int c0 = base + s[t] - o0;                 // absolute exclusive prefix
    int c1 = base + s[t + 256] - o1;
    __syncthreads();
    s[t] = c0; s[t + 256] = c1;                // become scatter cursors
    int* ofw = offs + (size_t)w * (NNODES + 1);
    int n0 = b * BSZ + t, n1 = b * BSZ + t + 256;
    if (n0 < NNODES) ofw[n0] = c0;
    if (n1 < NNODES) ofw[n1] = c1;
    __syncthreads();
    int2* sw = srcw + (size_t)w * NEDGES;
    for (int i = t; i < n; i += 256) {
        int2 e = st[i];
        int pos = atomicAdd(&s[(e.x >> 16) & (BSZ - 1)], 1);
        sw[pos] = make_int2(e.x & 0xffff, e.y);
    }
}

// ---- MFMA GEMM (batched): C_bf16[w] = A'[w] @ W[w], A' = elu(A+bias) if bias ----
__global__ __launch_bounds__(256) void gemm_mfma(
    const void* __restrict__ Avoid, size_t a_stride,        // elements per window
    const unsigned short* __restrict__ WtG, size_t wt_stride,
    const float* __restrict__ bias,                          // null or stride DIM
    unsigned short* __restrict__ C,                          // stride N*DIM
    int a_bf16)
{
    __shared__ unsigned short As[BM][136];
    __shared__ unsigned short Bs[DIM][136];
    const int t  = threadIdx.x;
    const int r0 = blockIdx.x * BM;
    const int w  = blockIdx.y;
    const unsigned short* Wt = WtG + (size_t)w * wt_stride;
    unsigned short* Cw = C + (size_t)w * NNODES * DIM;

    if (a_bf16) {
        const unsigned short* A = (const unsigned short*)Avoid + (size_t)w * a_stride;
        const float* bs = bias + (size_t)w * DIM;
        #pragma unroll
        for (int l = 0; l < 4; ++l) {
            int idx = t + l * 256;             // 1024 uint4 = 64x128 bf16
            int row = idx >> 4, c8 = (idx & 15) << 3;
            int gr  = r0 + row;
            uint4 v = make_uint4(0, 0, 0, 0);
            if (gr < NNODES) v = *(const uint4*)(A + (size_t)gr * DIM + c8);
            union { uint4 u; unsigned short s[8]; } in, ot;
            in.u = v;
            #pragma unroll
            for (int j = 0; j < 8; ++j) {
                float f = __uint_as_float((unsigned int)in.s[j] << 16);
                ot.s[j] = f2bf(eluf(f + bs[c8 + j]));
            }
            *(uint4*)&As[row][c8] = ot.u;
        }
    } else {
        const float* A = (const float*)Avoid + (size_t)w * a_stride;
        #pragma unroll
        for (int l = 0; l < 8; ++l) {
            int idx = t + l * 256;             // 2048 float4 = 64x128 fp32
            int row = idx >> 5, c4 = (idx & 31) << 2;
            int gr  = r0 + row;
            float4 v = make_float4(0.f, 0.f, 0.f, 0.f);
            if (gr < NNODES) v = *(const float4*)(A + (size_t)gr * DIM + c4);
            union { uint2 u; unsigned short s[4]; } ot;
            ot.s[0] = f2bf(v.x); ot.s[1] = f2bf(v.y);
            ot.s[2] = f2bf(v.z); ot.s[3] = f2bf(v.w);
            *(uint2*)&As[row][c4] = ot.u;
        }
    }
    // full W^T: 128x128 bf16 = 2048 uint4 chunks
    #pragma unroll
    for (int l = 0; l < 8; ++l) {
        int idx = t + l * 256;
        int n = idx >> 4, k8 = (idx & 15) << 3;
        *(uint4*)&Bs[n][k8] = *(const uint4*)(Wt + (size_t)n * DIM + k8);
    }
    __syncthreads();

    const int lane = t & 63, wv = t >> 6;
    const int mr = lane & 15, quad = lane >> 4;

    f32x4 acc[8];
    #pragma unroll
    for (int c = 0; c < 8; ++c) acc[c] = (f32x4){0.f, 0.f, 0.f, 0.f};

    const unsigned short* aptr = &As[wv * 16 + mr][quad * 8];
    #pragma unroll
    for (int kc = 0; kc < DIM; kc += 32) {
        bf16x8 a = *(const bf16x8*)(aptr + kc);
        #pragma unroll
        for (int c = 0; c < 8; ++c) {
            bf16x8 b = *(const bf16x8*)(&Bs[c * 16 + mr][quad * 8 + kc]);
            acc[c] = __builtin_amdgcn_mfma_f32_16x16x32_bf16(a, b, acc[c], 0, 0, 0);
        }
    }
    // Epilogue: bounce C tile through LDS (reuse As) -> coalesced uint4 stores
    __syncthreads();
    const int lr0 = wv * 16 + quad * 4;
    #pragma unroll
    for (int c = 0; c < 8; ++c) {
        int col = c * 16 + mr;
        #pragma unroll
        for (int r = 0; r < 4; ++r)
            As[lr0 + r][col] = f2bf(acc[c][r]);   // C/D: col=lane&15, row=quad*4+r
    }
    __syncthreads();
    #pragma unroll
    for (int l = 0; l < 4; ++l) {
        int idx = t + l * 256;                 // 1024 = 64 rows x 16 chunks
        int row = idx >> 4, c8 = (idx & 15) << 3;
        int gr = r0 + row;
        if (gr < NNODES)
            *(uint4*)(Cw + (size_t)gr * DIM + c8) = *(const uint4*)&As[row][c8];
    }
}

// ---- gather_agg (batched): one wave per dst, lane = 2 dims (dword per row) ----
// srcw for the whole dst is loaded ONCE lane-parallel (lane l -> edge beg+l),
// then each edge's (src,w) is broadcast via __shfl; all row loads issue
// back-to-back (no per-edge srcw latency hop).  deg>64 handled in chunks.
// mode 0: agg_bf16[w][dst] = sum.  mode 1: out_f32[w][dst] = elu(sum + bias).
__global__ __launch_bounds__(256) void gather_agg(
    const unsigned short* __restrict__ h,
    const int*  __restrict__ offs,
    const int2* __restrict__ srcw,
    const float* __restrict__ bias,
    void* __restrict__ outp,
    int mode)
{
    const int w = blockIdx.y;
    const unsigned short* hw = h + (size_t)w * NNODES * DIM;
    const int*  ow = offs + (size_t)w * (NNODES + 1);
    const int2* sw = srcw + (size_t)w * NEDGES;
    int wid  = (blockIdx.x * 256 + threadIdx.x) >> 6;
    int lane = threadIdx.x & 63;
    if (wid >= NNODES) return;
    const int beg = ow[wid], end = ow[wid + 1];
    const int d0 = lane * 2;
    float ax = 0.f, ay = 0.f;

    for (int c0 = beg; c0 < end; c0 += 64) {
        const int nc = min(64, end - c0);          // wave-uniform trip count
        int2 p = sw[min(c0 + lane, NEDGES - 1)];   // one coalesced srcw load
        int j = 0;
        for (; j + 4 <= nc; j += 4) {
            int   s0 = __shfl(p.x, j,     64);
            float w0 = __int_as_float(__shfl(p.y, j,     64));
            int   s1 = __shfl(p.x, j + 1, 64);
            float w1 = __int_as_float(__shfl(p.y, j + 1, 64));
            int   s2 = __shfl(p.x, j + 2, 64);
            float w2 = __int_as_float(__shfl(p.y, j + 2, 64));
            int   s3 = __shfl(p.x, j + 3, 64);
            float w3 = __int_as_float(__shfl(p.y, j + 3, 64));
            unsigned int v0 = *(const unsigned int*)(hw + (size_t)s0 * DIM + d0);
            unsigned int v1 = *(const unsigned int*)(hw + (size_t)s1 * DIM + d0);
            unsigned int v2 = *(const unsigned int*)(hw + (size_t)s2 * DIM + d0);
            unsigned int v3 = *(const unsigned int*)(hw + (size_t)s3 * DIM + d0);
            ax += w0 * bf16_lo(v0); ay += w0 * bf16_hi(v0);
            ax += w1 * bf16_lo(v1); ay += w1 * bf16_hi(v1);
            ax += w2 * bf16_lo(v2); ay += w2 * bf16_hi(v2);
            ax += w3 * bf16_lo(v3); ay += w3 * bf16_hi(v3);
        }
        for (; j < nc; ++j) {
            int   s0 = __shfl(p.x, j, 64);
            float w0 = __int_as_float(__shfl(p.y, j, 64));
            unsigned int v = *(const unsigned int*)(hw + (size_t)s0 * DIM + d0);
            ax += w0 * bf16_lo(v); ay += w0 * bf16_hi(v);
        }
    }

    if (mode == 0) {
        unsigned int pk = (unsigned int)f2bf(ax) | ((unsigned int)f2bf(ay) << 16);
        *((unsigned int*)outp + (size_t)w * NNODES * (DIM / 2)
                              + (size_t)wid * (DIM / 2) + lane) = pk;
    } else {
        const float* bs = bias + (size_t)w * DIM;
        float2 r;
        r.x = eluf(ax + bs[d0 + 0]);
        r.y = eluf(ay + bs[d0 + 1]);
        *(float2*)((float*)outp + (size_t)w * NNODES * DIM + (size_t)wid * DIM + d0) = r;
    }
}

extern "C" void kernel_launch(void* const* d_in, const int* in_sizes, int n_in,
                              void* d_out, int out_size, void* d_ws, size_t ws_size,
                              hipStream_t stream) {
    const float* x           = (const float*)d_in[0];
    const int*   edge_index  = (const int*)  d_in[1];
    const float* edge_weight = (const float*)d_in[2];
    const float* W0          = (const float*)d_in[3];
    const float* b0          = (const float*)d_in[4];
    const float* W1          = (const float*)d_in[5];
    const float* b1          = (const float*)d_in[6];
    float*       out         = (float*)d_out;

    const size_t ND = (size_t)NNODES * DIM;

    // Workspace per batched-window: h + agg (bf16) + wt + srcw + offs + bucket meta
    auto need = [&](int nb) -> size_t {
        return (size_t)nb * (ND * 2 + ND * 2 + 2 * DIM * DIM * 2
                             + (size_t)NEDGES * 8
                             + (size_t)(NNODES + 1) * 4
                             + (size_t)NB2 * 4 * 2 + (size_t)(NB2 + 1) * 4);
    };
    int nb = WINDOW;
    while (nb > 1 && need(nb) > ws_size) nb >>= 1;

    char* p = (char*)d_ws;
    unsigned short* h_buf   = (unsigned short*)p;  p += (size_t)nb * ND * 2;
    unsigned short* agg_buf = (unsigned short*)p;  p += (size_t)nb * ND * 2;
    unsigned short* wt      = (unsigned short*)p;  p += (size_t)nb * 2 * DIM * DIM * 2;
    int2*           srcw    = (int2*)p;            p += (size_t)nb * NEDGES * 8;
    int*            offs    = (int*)p;             p += (size_t)nb * (NNODES + 1) * 4;
    int*            bcnt    = (int*)p;             p += (size_t)nb * NB2 * 4;
    int*            bcur    = (int*)p;             p += (size_t)nb * NB2 * 4;
    int*            bbase   = (int*)p;             p += (size_t)nb * (NB2 + 1) * 4;
    int2*           stage   = (int2*)h_buf;        // reuse h_buf before gemm hop 1

    const dim3 hg(P1B, nb);                           // multi-split blocks
    const dim3 gg((NNODES + BM - 1) / BM, nb);        // gemm tiles
    const dim3 ag((NNODES * 64 + 255) / 256, nb);     // one wave per dst
    const dim3 bg(NB2, nb);                           // per-bucket pass
    const int  prep_grid = (nb * 2 * DIM * DIM + 255) / 256;

    for (int w0 = 0; w0 < WINDOW; w0 += nb) {
        const float* W0g = W0 + (size_t)w0 * DIM * DIM;
        const float* W1g = W1 + (size_t)w0 * DIM * DIM;
        const int*   eig = edge_index  + (size_t)w0 * 2 * NEDGES;
        const float* ewg = edge_weight + (size_t)w0 * NEDGES;

        prep_kernel <<<prep_grid, 256, 0, stream>>>(W0g, W1g, wt, bcnt, bcur, nb);
        bhist_kernel<<<hg, 256, 0, stream>>>(eig, bcnt);
        bscan_kernel<<<nb, 128, 0, stream>>>(bcnt, bbase, offs);
        bucket_p1   <<<hg, 256, 0, stream>>>(eig, ewg, bbase, bcur, stage);
        bucket_p2   <<<bg, 256, 0, stream>>>(stage, bbase, offs, srcw);

        // hop 1: h = x @ W0 ; agg = gather(h)   (gemm overwrites stage == h_buf)
        gemm_mfma <<<gg, 256, 0, stream>>>(x + (size_t)w0 * ND, ND,
                                           wt, 2 * DIM * DIM, nullptr, h_buf, 0);
        gather_agg<<<ag, 256, 0, stream>>>(h_buf, offs, srcw, nullptr, agg_buf, 0);
        // hop 2: h = elu(agg+b0) @ W1 ; out = elu(gather(h) + b1)
        gemm_mfma <<<gg, 256, 0, stream>>>(agg_buf, ND,
                                           wt + DIM * DIM, 2 * DIM * DIM,
                                           b0 + (size_t)w0 * DIM, h_buf, 1);
        gather_agg<<<ag, 256, 0, stream>>>(h_buf, offs, srcw,
                                           b1 + (size_t)w0 * DIM,
                                           out + (size_t)w0 * ND, 1);
    }
}

// Round 7
// 419.166 us; speedup vs baseline: 1.2054x; 1.0953x over previous
//
#include <hip/hip_runtime.h>
#include <hip/hip_bf16.h>
#include <math.h>

#define WINDOW 4
#define NNODES 50000
#define NEDGES 400000
#define DIM 128
#define BM 64

// multi-split geometry: coarse bucket = dst >> 9 (512 dsts per bucket)
#define BSH 9
#define BSZ 512
#define NB2 ((NNODES + BSZ - 1) / BSZ)         // 98 buckets
#define EPB 4096                               // edges per p1/bhist block
#define P1B ((NEDGES + EPB - 1) / EPB)         // 98 blocks per window

typedef short bf16x8 __attribute__((ext_vector_type(8)));
typedef float f32x4  __attribute__((ext_vector_type(4)));

__device__ __forceinline__ float eluf(float x) {
    return x > 0.0f ? x : expm1f(x);
}
__device__ __forceinline__ float bf16_lo(unsigned int v) {
    return __uint_as_float(v << 16);
}
__device__ __forceinline__ float bf16_hi(unsigned int v) {
    return __uint_as_float(v & 0xffff0000u);
}
__device__ __forceinline__ unsigned short f2bf(float f) {
    __hip_bfloat16 h = __float2bfloat16(f);   // RNE
    return *(unsigned short*)&h;
}

// ---- prep: zero bcnt/bcur + cast/transpose W0,W1 -> wt[nb][2][128][128] ----
__global__ __launch_bounds__(256) void prep_kernel(
    const float* __restrict__ W0, const float* __restrict__ W1,
    unsigned short* __restrict__ wt, int* __restrict__ bcnt,
    int* __restrict__ bcur, int nb)
{
    int i = blockIdx.x * 256 + threadIdx.x;
    int ncast = nb * 2 * DIM * DIM;            // nb*32768
    if (i < ncast) {
        int w   = i >> 15;
        int rem = i & 32767;
        int m   = rem >> 14;                   // 0:W0 1:W1
        int j   = rem & 16383;
        int n   = j >> 7, k = j & 127;
        const float* Ws = (m ? W1 : W0) + (size_t)w * DIM * DIM;
        wt[i] = f2bf(Ws[k * DIM + n]);         // wt[(w*2+m)*16384 + n*128 + k]
    }
    if (i < nb * NB2) { bcnt[i] = 0; bcur[i] = 0; }
}

// ---- bhist: block-aggregated coarse histogram (<=98 global atomics/block) ----
__global__ __launch_bounds__(256) void bhist_kernel(
    const int* __restrict__ ei, int* __restrict__ bcnt)
{
    const int w = blockIdx.y, b0 = blockIdx.x * EPB;
    const int t = threadIdx.x;
    __shared__ int lh[NB2];
    for (int i = t; i < NB2; i += 256) lh[i] = 0;
    __syncthreads();
    const int* dst = ei + (size_t)w * 2 * NEDGES + NEDGES;
    #pragma unroll
    for (int j = 0; j < EPB / 256; ++j) {
        int e = b0 + j * 256 + t;
        if (e < NEDGES) atomicAdd(&lh[dst[e] >> BSH], 1);
    }
    __syncthreads();
    for (int i = t; i < NB2; i += 256)
        if (lh[i]) atomicAdd(&bcnt[w * NB2 + i], lh[i]);
}

// ---- bscan: exclusive scan of 98 bucket counts (one 128-thr block/window) ----
__global__ __launch_bounds__(128) void bscan_kernel(
    const int* __restrict__ bcnt, int* __restrict__ bbase, int* __restrict__ offs)
{
    const int w = blockIdx.x;
    const int t = threadIdx.x;
    __shared__ int s[128];
    int orig = (t < NB2) ? bcnt[w * NB2 + t] : 0;
    s[t] = orig;
    __syncthreads();
    for (int off = 1; off < 128; off <<= 1) {
        int v = (t >= off) ? s[t - off] : 0;
        __syncthreads();
        s[t] += v;
        __syncthreads();
    }
    if (t < NB2) bbase[w * (NB2 + 1) + t] = s[t] - orig;       // exclusive
    if (t == NB2 - 1) {
        bbase[w * (NB2 + 1) + NB2] = s[t];                     // total == NEDGES
        offs[(size_t)w * (NNODES + 1) + NNODES] = s[t];
    }
}

// ---- bucket_p1: block multi-split. One global atomic per (block,bucket); ----
// ---- each bucket's run written as a contiguous burst by a single block. ----
__global__ __launch_bounds__(256) void bucket_p1(
    const int* __restrict__ ei, const float* __restrict__ ew,
    const int* __restrict__ bbase, int* __restrict__ bcur,
    int2* __restrict__ stage)
{
    const int w = blockIdx.y, b0 = blockIdx.x * EPB;
    const int t = threadIdx.x;
    __shared__ int lh[NB2];
    __shared__ int gb[NB2];
    for (int i = t; i < NB2; i += 256) lh[i] = 0;
    __syncthreads();
    const int*   eiw = ei + (size_t)w * 2 * NEDGES;
    const float* eww = ew + (size_t)w * NEDGES;
    int  tag[EPB / 256];           // (bucket<<12) | local_rank, -1 = invalid
    int2 pk[EPB / 256];
    #pragma unroll
    for (int j = 0; j < EPB / 256; ++j) {
        int e = b0 + j * 256 + t;
        if (e < NEDGES) {
            int d = eiw[NEDGES + e], s = eiw[e];
            int b = d >> BSH;
            int r = atomicAdd(&lh[b], 1);      // local rank within (block,bucket)
            tag[j] = (b << 12) | r;            // r < 4096
            pk[j]  = make_int2(s | ((d & (BSZ - 1)) << 16),
                               __float_as_int(eww[e]));
        } else tag[j] = -1;
    }
    __syncthreads();
    for (int i = t; i < NB2; i += 256)
        gb[i] = bbase[w * (NB2 + 1) + i]
              + (lh[i] ? atomicAdd(&bcur[w * NB2 + i], lh[i]) : 0);
    __syncthreads();
    int2* st = stage + (size_t)w * NEDGES;
    #pragma unroll
    for (int j = 0; j < EPB / 256; ++j) {
        if (tag[j] >= 0)
            st[gb[tag[j] >> 12] + (tag[j] & 4095)] = pk[j];
    }
}

// ---- bucket_p2: per-bucket per-dst sort -> offs[dst] + dst-sorted srcw ----
// One block per (bucket, window): ~4K edges, dense 32KB output (full lines).
// Also produces the per-dst CSR offsets (replaces hist + 3-phase scan).
__global__ __launch_bounds__(256) void bucket_p2(
    const int2* __restrict__ stage, const int* __restrict__ bbase,
    int* __restrict__ offs, int2* __restrict__ srcw)
{
    const int b = blockIdx.x, w = blockIdx.y;
    const int t = threadIdx.x;
    __shared__ int s[BSZ];
    const int base = bbase[w * (NB2 + 1) + b];
    const int n    = bbase[w * (NB2 + 1) + b + 1] - base;
    s[t] = 0; s[t + 256] = 0;
    __syncthreads();
    const int2* st = stage + (size_t)w * NEDGES + base;
    for (int i = t; i < n; i += 256)
        atomicAdd(&s[(st[i].x >> 16) & (BSZ - 1)], 1);
    __syncthreads();
    int o0 = s[t], o1 = s[t + 256];
    // inclusive Hillis-Steele over 512 counters, 2 elems/thread
    for (int off = 1; off < BSZ; off <<= 1) {
        int a0 = (t >= off) ? s[t - off] : 0;
        int a1 = (t + 256 >= off) ? s[t + 256 - off] : 0;
        __syncthreads();
        s[t] += a0; s[t + 256] += a1;
        __syncthreads();
    }
    int c0 = base + s[t] - o0;                 // absolute exclusive prefix
    int c1 = base + s[t + 256] - o1;
    __syncthreads();
    s[t] = c0; s[t + 256] = c1;                // become scatter cursors
    int* ofw = offs + (size_t)w * (NNODES + 1);
    int n0 = b * BSZ + t, n1 = b * BSZ + t + 256;
    if (n0 < NNODES) ofw[n0] = c0;
    if (n1 < NNODES) ofw[n1] = c1;
    __syncthreads();
    int2* sw = srcw + (size_t)w * NEDGES;
    for (int i = t; i < n; i += 256) {
        int2 e = st[i];
        int pos = atomicAdd(&s[(e.x >> 16) & (BSZ - 1)], 1);
        sw[pos] = make_int2(e.x & 0xffff, e.y);
    }
}

// ---- MFMA GEMM (batched): C_bf16[w] = A'[w] @ W[w], A' = elu(A+bias) if bias ----
__global__ __launch_bounds__(256) void gemm_mfma(
    const void* __restrict__ Avoid, size_t a_stride,        // elements per window
    const unsigned short* __restrict__ WtG, size_t wt_stride,
    const float* __restrict__ bias,                          // null or stride DIM
    unsigned short* __restrict__ C,                          // stride N*DIM
    int a_bf16)
{
    __shared__ unsigned short As[BM][136];
    __shared__ unsigned short Bs[DIM][136];
    const int t  = threadIdx.x;
    const int r0 = blockIdx.x * BM;
    const int w  = blockIdx.y;
    const unsigned short* Wt = WtG + (size_t)w * wt_stride;
    unsigned short* Cw = C + (size_t)w * NNODES * DIM;

    if (a_bf16) {
        const unsigned short* A = (const unsigned short*)Avoid + (size_t)w * a_stride;
        const float* bs = bias + (size_t)w * DIM;
        #pragma unroll
        for (int l = 0; l < 4; ++l) {
            int idx = t + l * 256;             // 1024 uint4 = 64x128 bf16
            int row = idx >> 4, c8 = (idx & 15) << 3;
            int gr  = r0 + row;
            uint4 v = make_uint4(0, 0, 0, 0);
            if (gr < NNODES) v = *(const uint4*)(A + (size_t)gr * DIM + c8);
            union { uint4 u; unsigned short s[8]; } in, ot;
            in.u = v;
            #pragma unroll
            for (int j = 0; j < 8; ++j) {
                float f = __uint_as_float((unsigned int)in.s[j] << 16);
                ot.s[j] = f2bf(eluf(f + bs[c8 + j]));
            }
            *(uint4*)&As[row][c8] = ot.u;
        }
    } else {
        const float* A = (const float*)Avoid + (size_t)w * a_stride;
        #pragma unroll
        for (int l = 0; l < 8; ++l) {
            int idx = t + l * 256;             // 2048 float4 = 64x128 fp32
            int row = idx >> 5, c4 = (idx & 31) << 2;
            int gr  = r0 + row;
            float4 v = make_float4(0.f, 0.f, 0.f, 0.f);
            if (gr < NNODES) v = *(const float4*)(A + (size_t)gr * DIM + c4);
            union { uint2 u; unsigned short s[4]; } ot;
            ot.s[0] = f2bf(v.x); ot.s[1] = f2bf(v.y);
            ot.s[2] = f2bf(v.z); ot.s[3] = f2bf(v.w);
            *(uint2*)&As[row][c4] = ot.u;
        }
    }
    // full W^T: 128x128 bf16 = 2048 uint4 chunks
    #pragma unroll
    for (int l = 0; l < 8; ++l) {
        int idx = t + l * 256;
        int n = idx >> 4, k8 = (idx & 15) << 3;
        *(uint4*)&Bs[n][k8] = *(const uint4*)(Wt + (size_t)n * DIM + k8);
    }
    __syncthreads();

    const int lane = t & 63, wv = t >> 6;
    const int mr = lane & 15, quad = lane >> 4;

    f32x4 acc[8];
    #pragma unroll
    for (int c = 0; c < 8; ++c) acc[c] = (f32x4){0.f, 0.f, 0.f, 0.f};

    const unsigned short* aptr = &As[wv * 16 + mr][quad * 8];
    #pragma unroll
    for (int kc = 0; kc < DIM; kc += 32) {
        bf16x8 a = *(const bf16x8*)(aptr + kc);
        #pragma unroll
        for (int c = 0; c < 8; ++c) {
            bf16x8 b = *(const bf16x8*)(&Bs[c * 16 + mr][quad * 8 + kc]);
            acc[c] = __builtin_amdgcn_mfma_f32_16x16x32_bf16(a, b, acc[c], 0, 0, 0);
        }
    }
    // Epilogue: bounce C tile through LDS (reuse As) -> coalesced uint4 stores
    __syncthreads();
    const int lr0 = wv * 16 + quad * 4;
    #pragma unroll
    for (int c = 0; c < 8; ++c) {
        int col = c * 16 + mr;
        #pragma unroll
        for (int r = 0; r < 4; ++r)
            As[lr0 + r][col] = f2bf(acc[c][r]);   // C/D: col=lane&15, row=quad*4+r
    }
    __syncthreads();
    #pragma unroll
    for (int l = 0; l < 4; ++l) {
        int idx = t + l * 256;                 // 1024 = 64 rows x 16 chunks
        int row = idx >> 4, c8 = (idx & 15) << 3;
        int gr = r0 + row;
        if (gr < NNODES)
            *(uint4*)(Cw + (size_t)gr * DIM + c8) = *(const uint4*)&As[row][c8];
    }
}

// ---- helper: round-5 style single-dst chunked gather (fallback path) ----
__device__ __forceinline__ void gather_one(
    const unsigned short* __restrict__ hw, const int2* __restrict__ sw,
    int beg, int end, int lane, int d0, float& ax, float& ay)
{
    for (int c0 = beg; c0 < end; c0 += 64) {
        const int nc = min(64, end - c0);
        int2 p = sw[min(c0 + lane, NEDGES - 1)];
        int j = 0;
        for (; j + 4 <= nc; j += 4) {
            int   s0 = __shfl(p.x, j,     64);
            float w0 = __int_as_float(__shfl(p.y, j,     64));
            int   s1 = __shfl(p.x, j + 1, 64);
            float w1 = __int_as_float(__shfl(p.y, j + 1, 64));
            int   s2 = __shfl(p.x, j + 2, 64);
            float w2 = __int_as_float(__shfl(p.y, j + 2, 64));
            int   s3 = __shfl(p.x, j + 3, 64);
            float w3 = __int_as_float(__shfl(p.y, j + 3, 64));
            unsigned int v0 = *(const unsigned int*)(hw + (size_t)s0 * DIM + d0);
            unsigned int v1 = *(const unsigned int*)(hw + (size_t)s1 * DIM + d0);
            unsigned int v2 = *(const unsigned int*)(hw + (size_t)s2 * DIM + d0);
            unsigned int v3 = *(const unsigned int*)(hw + (size_t)s3 * DIM + d0);
            ax += w0 * bf16_lo(v0); ay += w0 * bf16_hi(v0);
            ax += w1 * bf16_lo(v1); ay += w1 * bf16_hi(v1);
            ax += w2 * bf16_lo(v2); ay += w2 * bf16_hi(v2);
            ax += w3 * bf16_lo(v3); ay += w3 * bf16_hi(v3);
        }
        for (; j < nc; ++j) {
            int   s0 = __shfl(p.x, j, 64);
            float w0 = __int_as_float(__shfl(p.y, j, 64));
            unsigned int v = *(const unsigned int*)(hw + (size_t)s0 * DIM + d0);
            ax += w0 * bf16_lo(v); ay += w0 * bf16_hi(v);
        }
    }
}

// ---- gather_agg (batched): one wave per TWO dsts (contiguous edge ranges) ----
// One srcw window covers both dsts; dual-stream 4-wide main loop keeps
// 8 independent row loads in flight per wave (2x the single-dst version).
// Common-prefix phase is mask-free; short remainder of the longer stream is
// masked 4-wide. Combined degree > 64 (P~1e-18) falls back to gather_one.
// mode 0: agg_bf16[w][dst] = sum.  mode 1: out_f32[w][dst] = elu(sum + bias).
__global__ __launch_bounds__(256) void gather_agg(
    const unsigned short* __restrict__ h,
    const int*  __restrict__ offs,
    const int2* __restrict__ srcw,
    const float* __restrict__ bias,
    void* __restrict__ outp,
    int mode)
{
    const int w = blockIdx.y;
    const unsigned short* hw = h + (size_t)w * NNODES * DIM;
    const int*  ow = offs + (size_t)w * (NNODES + 1);
    const int2* sw = srcw + (size_t)w * NEDGES;
    const int gid  = (blockIdx.x * 256 + threadIdx.x) >> 6;
    const int lane = threadIdx.x & 63;
    const int dA = gid * 2;
    if (dA >= NNODES) return;                  // dB = dA+1 < NNODES (N even)
    const int off_l = ow[dA + min(lane, 2)];
    const int b0 = __shfl(off_l, 0, 64);
    const int b1 = __shfl(off_l, 1, 64);
    const int b2 = __shfl(off_l, 2, 64);
    const int d0 = lane * 2;
    const int na = b1 - b0, nb = b2 - b1;
    float axA = 0.f, ayA = 0.f, axB = 0.f, ayB = 0.f;

    if (b2 - b0 <= 64) {
        if (b2 > b0) {
            int2 p = sw[min(b0 + lane, NEDGES - 1)];
            const int ob = na;                 // stream B local offset
            const int Tc = min(na, nb);
            int j = 0;
            // phase 1: both streams 4-wide, mask-free (8 loads in flight)
            for (; j + 4 <= Tc; j += 4) {
                int   sA0=__shfl(p.x,j  ,64);    float wA0=__int_as_float(__shfl(p.y,j  ,64));
                int   sA1=__shfl(p.x,j+1,64);    float wA1=__int_as_float(__shfl(p.y,j+1,64));
                int   sA2=__shfl(p.x,j+2,64);    float wA2=__int_as_float(__shfl(p.y,j+2,64));
                int   sA3=__shfl(p.x,j+3,64);    float wA3=__int_as_float(__shfl(p.y,j+3,64));
                int   sB0=__shfl(p.x,ob+j  ,64); float wB0=__int_as_float(__shfl(p.y,ob+j  ,64));
                int   sB1=__shfl(p.x,ob+j+1,64); float wB1=__int_as_float(__shfl(p.y,ob+j+1,64));
                int   sB2=__shfl(p.x,ob+j+2,64); float wB2=__int_as_float(__shfl(p.y,ob+j+2,64));
                int   sB3=__shfl(p.x,ob+j+3,64); float wB3=__int_as_float(__shfl(p.y,ob+j+3,64));
                unsigned int vA0=*(const unsigned int*)(hw+(size_t)sA0*DIM+d0);
                unsigned int vA1=*(const unsigned int*)(hw+(size_t)sA1*DIM+d0);
                unsigned int vA2=*(const unsigned int*)(hw+(size_t)sA2*DIM+d0);
                unsigned int vA3=*(const unsigned int*)(hw+(size_t)sA3*DIM+d0);
                unsigned int vB0=*(const unsigned int*)(hw+(size_t)sB0*DIM+d0);
                unsigned int vB1=*(const unsigned int*)(hw+(size_t)sB1*DIM+d0);
                unsigned int vB2=*(const unsigned int*)(hw+(size_t)sB2*DIM+d0);
                unsigned int vB3=*(const unsigned int*)(hw+(size_t)sB3*DIM+d0);
                axA += wA0*bf16_lo(vA0); ayA += wA0*bf16_hi(vA0);
                axA += wA1*bf16_lo(vA1); ayA += wA1*bf16_hi(vA1);
                axA += wA2*bf16_lo(vA2); ayA += wA2*bf16_hi(vA2);
                axA += wA3*bf16_lo(vA3); ayA += wA3*bf16_hi(vA3);
                axB += wB0*bf16_lo(vB0); ayB += wB0*bf16_hi(vB0);
                axB += wB1*bf16_lo(vB1); ayB += wB1*bf16_hi(vB1);
                axB += wB2*bf16_lo(vB2); ayB += wB2*bf16_hi(vB2);
                axB += wB3*bf16_lo(vB3); ayB += wB3*bf16_hi(vB3);
            }
            // phase 1 tail: both streams per-edge (2 loads in flight)
            for (; j < Tc; ++j) {
                int   sA=__shfl(p.x,j   ,64);   float wA=__int_as_float(__shfl(p.y,j   ,64));
                int   sB=__shfl(p.x,ob+j,64);   float wB=__int_as_float(__shfl(p.y,ob+j,64));
                unsigned int vA=*(const unsigned int*)(hw+(size_t)sA*DIM+d0);
                unsigned int vB=*(const unsigned int*)(hw+(size_t)sB*DIM+d0);
                axA += wA*bf16_lo(vA); ayA += wA*bf16_hi(vA);
                axB += wB*bf16_lo(vB); ayB += wB*bf16_hi(vB);
            }
            // phase 2: remainder of the longer stream, masked 4-wide
            if (na > nb) {
                for (int j2 = Tc; j2 < na; j2 += 4) {
                    int e1=j2+1, e2=j2+2, e3=j2+3;
                    int i1=min(e1,na-1), i2=min(e2,na-1), i3=min(e3,na-1);
                    int   s0=__shfl(p.x,j2,64); float w0=__int_as_float(__shfl(p.y,j2,64));
                    int   s1=__shfl(p.x,i1,64); float w1=__int_as_float(__shfl(p.y,i1,64));
                    int   s2=__shfl(p.x,i2,64); float w2=__int_as_float(__shfl(p.y,i2,64));
                    int   s3=__shfl(p.x,i3,64); float w3=__int_as_float(__shfl(p.y,i3,64));
                    if (e1 >= na) w1 = 0.f;
                    if (e2 >= na) w2 = 0.f;
                    if (e3 >= na) w3 = 0.f;
                    unsigned int v0=*(const unsigned int*)(hw+(size_t)s0*DIM+d0);
                    unsigned int v1=*(const unsigned int*)(hw+(size_t)s1*DIM+d0);
                    unsigned int v2=*(const unsigned int*)(hw+(size_t)s2*DIM+d0);
                    unsigned int v3=*(const unsigned int*)(hw+(size_t)s3*DIM+d0);
                    axA += w0*bf16_lo(v0); ayA += w0*bf16_hi(v0);
                    axA += w1*bf16_lo(v1); ayA += w1*bf16_hi(v1);
                    axA += w2*bf16_lo(v2); ayA += w2*bf16_hi(v2);
                    axA += w3*bf16_lo(v3); ayA += w3*bf16_hi(v3);
                }
            } else if (nb > na) {
                for (int j2 = Tc; j2 < nb; j2 += 4) {
                    int e1=j2+1, e2=j2+2, e3=j2+3;
                    int i1=ob+min(e1,nb-1), i2=ob+min(e2,nb-1), i3=ob+min(e3,nb-1);
                    int   s0=__shfl(p.x,ob+j2,64); float w0=__int_as_float(__shfl(p.y,ob+j2,64));
                    int   s1=__shfl(p.x,i1,64);    float w1=__int_as_float(__shfl(p.y,i1,64));
                    int   s2=__shfl(p.x,i2,64);    float w2=__int_as_float(__shfl(p.y,i2,64));
                    int   s3=__shfl(p.x,i3,64);    float w3=__int_as_float(__shfl(p.y,i3,64));
                    if (e1 >= nb) w1 = 0.f;
                    if (e2 >= nb) w2 = 0.f;
                    if (e3 >= nb) w3 = 0.f;
                    unsigned int v0=*(const unsigned int*)(hw+(size_t)s0*DIM+d0);
                    unsigned int v1=*(const unsigned int*)(hw+(size_t)s1*DIM+d0);
                    unsigned int v2=*(const unsigned int*)(hw+(size_t)s2*DIM+d0);
                    unsigned int v3=*(const unsigned int*)(hw+(size_t)s3*DIM+d0);
                    axB += w0*bf16_lo(v0); ayB += w0*bf16_hi(v0);
                    axB += w1*bf16_lo(v1); ayB += w1*bf16_hi(v1);
                    axB += w2*bf16_lo(v2); ayB += w2*bf16_hi(v2);
                    axB += w3*bf16_lo(v3); ayB += w3*bf16_hi(v3);
                }
            }
        }
    } else {
        // rare: combined degree > 64 — per-dst chunked path
        gather_one(hw, sw, b0, b1, lane, d0, axA, ayA);
        gather_one(hw, sw, b1, b2, lane, d0, axB, ayB);
    }

    if (mode == 0) {
        unsigned int pkA = (unsigned int)f2bf(axA) | ((unsigned int)f2bf(ayA) << 16);
        unsigned int pkB = (unsigned int)f2bf(axB) | ((unsigned int)f2bf(ayB) << 16);
        unsigned int* ob_ = (unsigned int*)outp + (size_t)w * NNODES * (DIM / 2);
        ob_[(size_t)dA * (DIM / 2) + lane]       = pkA;
        ob_[(size_t)(dA + 1) * (DIM / 2) + lane] = pkB;
    } else {
        const float* bs = bias + (size_t)w * DIM;
        float bx = bs[d0], by = bs[d0 + 1];
        float* op = (float*)outp + (size_t)w * NNODES * DIM;
        float2 rA, rB;
        rA.x = eluf(axA + bx); rA.y = eluf(ayA + by);
        rB.x = eluf(axB + bx); rB.y = eluf(ayB + by);
        *(float2*)(op + (size_t)dA * DIM + d0)       = rA;
        *(float2*)(op + (size_t)(dA + 1) * DIM + d0) = rB;
    }
}

extern "C" void kernel_launch(void* const* d_in, const int* in_sizes, int n_in,
                              void* d_out, int out_size, void* d_ws, size_t ws_size,
                              hipStream_t stream) {
    const float* x           = (const float*)d_in[0];
    const int*   edge_index  = (const int*)  d_in[1];
    const float* edge_weight = (const float*)d_in[2];
    const float* W0          = (const float*)d_in[3];
    const float* b0          = (const float*)d_in[4];
    const float* W1          = (const float*)d_in[5];
    const float* b1          = (const float*)d_in[6];
    float*       out         = (float*)d_out;

    const size_t ND = (size_t)NNODES * DIM;

    // Workspace per batched-window: h + agg (bf16) + wt + srcw + offs + bucket meta
    auto need = [&](int nb) -> size_t {
        return (size_t)nb * (ND * 2 + ND * 2 + 2 * DIM * DIM * 2
                             + (size_t)NEDGES * 8
                             + (size_t)(NNODES + 1) * 4
                             + (size_t)NB2 * 4 * 2 + (size_t)(NB2 + 1) * 4);
    };
    int nb = WINDOW;
    while (nb > 1 && need(nb) > ws_size) nb >>= 1;

    char* p = (char*)d_ws;
    unsigned short* h_buf   = (unsigned short*)p;  p += (size_t)nb * ND * 2;
    unsigned short* agg_buf = (unsigned short*)p;  p += (size_t)nb * ND * 2;
    unsigned short* wt      = (unsigned short*)p;  p += (size_t)nb * 2 * DIM * DIM * 2;
    int2*           srcw    = (int2*)p;            p += (size_t)nb * NEDGES * 8;
    int*            offs    = (int*)p;             p += (size_t)nb * (NNODES + 1) * 4;
    int*            bcnt    = (int*)p;             p += (size_t)nb * NB2 * 4;
    int*            bcur    = (int*)p;             p += (size_t)nb * NB2 * 4;
    int*            bbase   = (int*)p;             p += (size_t)nb * (NB2 + 1) * 4;
    int2*           stage   = (int2*)h_buf;        // reuse h_buf before gemm hop 1

    const dim3 hg(P1B, nb);                           // multi-split blocks
    const dim3 gg((NNODES + BM - 1) / BM, nb);        // gemm tiles
    const dim3 ag(((NNODES / 2) * 64 + 255) / 256, nb); // one wave per dst PAIR
    const dim3 bg(NB2, nb);                           // per-bucket pass
    const int  prep_grid = (nb * 2 * DIM * DIM + 255) / 256;

    for (int w0 = 0; w0 < WINDOW; w0 += nb) {
        const float* W0g = W0 + (size_t)w0 * DIM * DIM;
        const float* W1g = W1 + (size_t)w0 * DIM * DIM;
        const int*   eig = edge_index  + (size_t)w0 * 2 * NEDGES;
        const float* ewg = edge_weight + (size_t)w0 * NEDGES;

        prep_kernel <<<prep_grid, 256, 0, stream>>>(W0g, W1g, wt, bcnt, bcur, nb);
        bhist_kernel<<<hg, 256, 0, stream>>>(eig, bcnt);
        bscan_kernel<<<nb, 128, 0, stream>>>(bcnt, bbase, offs);
        bucket_p1   <<<hg, 256, 0, stream>>>(eig, ewg, bbase, bcur, stage);
        bucket_p2   <<<bg, 256, 0, stream>>>(stage, bbase, offs, srcw);

        // hop 1: h = x @ W0 ; agg = gather(h)   (gemm overwrites stage == h_buf)
        gemm_mfma <<<gg, 256, 0, stream>>>(x + (size_t)w0 * ND, ND,
                                           wt, 2 * DIM * DIM, nullptr, h_buf, 0);
        gather_agg<<<ag, 256, 0, stream>>>(h_buf, offs, srcw, nullptr, agg_buf, 0);
        // hop 2: h = elu(agg+b0) @ W1 ; out = elu(gather(h) + b1)
        gemm_mfma <<<gg, 256, 0, stream>>>(agg_buf, ND,
                                           wt + DIM * DIM, 2 * DIM * DIM,
                                           b0 + (size_t)w0 * DIM, h_buf, 1);
        gather_agg<<<ag, 256, 0, stream>>>(h_buf, offs, srcw,
                                           b1 + (size_t)w0 * DIM,
                                           out + (size_t)w0 * ND, 1);
    }
}